// Round 1
// baseline (1230.597 us; speedup 1.0000x reference)
//
#include <hip/hip_runtime.h>
#include <math.h>

// Problem constants
#define BATCH 4
#define CH    48          // DIM
#define QKVC  144         // 3*DIM
#define HID   192         // DIM*EXP
#define HEADS 8
#define HC    6           // DIM/HEADS
#define IMG   256         // H == W
#define HWSZ  65536       // H*W

// ---------------------------------------------------------------------------
// K1: per-pixel LayerNorm over C=48 + 1x1 conv to 144 qkv channels.
// One thread per pixel. Weight reads are wave-uniform -> s_load (SGPR).
// ---------------------------------------------------------------------------
__global__ __launch_bounds__(256) void k1_ln_qkv(
    const float* __restrict__ x, const float* __restrict__ ln_g, const float* __restrict__ ln_b,
    const float* __restrict__ wq, const float* __restrict__ bq,
    float* __restrict__ qkv)
{
    const int tid = threadIdx.x;
    const int b = blockIdx.x >> 8;                    // 256 blocks per batch image
    const int p = ((blockIdx.x & 255) << 8) | tid;    // pixel index in [0,65536)
    const float* xb = x + ((size_t)b * CH << 16) + p;
    float y[CH];
    float mu = 0.f;
#pragma unroll
    for (int c = 0; c < CH; ++c) { y[c] = xb[(size_t)c << 16]; mu += y[c]; }
    mu *= (1.0f / CH);
    float var = 0.f;
#pragma unroll
    for (int c = 0; c < CH; ++c) { float d = y[c] - mu; var += d * d; }
    const float rs = rsqrtf(var * (1.0f / CH) + 1e-5f);
#pragma unroll
    for (int c = 0; c < CH; ++c) y[c] = (y[c] - mu) * rs * ln_g[c] + ln_b[c];

    float* qb = qkv + ((size_t)b * QKVC << 16) + p;
    for (int o = 0; o < QKVC; ++o) {
        float acc = bq[o];
#pragma unroll
        for (int c = 0; c < CH; ++c) acc += wq[o * CH + c] * y[c];
        qb[(size_t)o << 16] = acc;
    }
}

// ---------------------------------------------------------------------------
// K2: depthwise 3x3 over the 18 channels of one head (6 q, 6 k, 6 v),
// per (batch, head, group-of-4 16x16 tiles). Writes dw-conv'd v to global;
// accumulates Gram S[6][6] = sum_n q_c*k_d and squared norms, block-reduces,
// atomicAdds into stats[b][h][48]  (layout: 36 gram | 6 qn2 | 6 kn2).
// ---------------------------------------------------------------------------
__global__ __launch_bounds__(256) void k2_dw_gram(
    const float* __restrict__ qkv, const float* __restrict__ wdw, const float* __restrict__ bdw,
    float* __restrict__ vout, float* __restrict__ stats)
{
    __shared__ float tile[18][324];   // 18 channels x 18x18 halo tile
    __shared__ float red[4][48];
    const int tid = threadIdx.x;
    const int blk = blockIdx.x;       // B * 8 * 64
    const int b  = blk >> 9;
    const int h  = (blk >> 6) & 7;
    const int t4 = blk & 63;

    float S[6][6], qn2[6], kn2[6];
#pragma unroll
    for (int c = 0; c < 6; ++c) {
        qn2[c] = 0.f; kn2[c] = 0.f;
#pragma unroll
        for (int d = 0; d < 6; ++d) S[c][d] = 0.f;
    }
    const int iy = tid >> 4, ix = tid & 15;

    for (int tt = 0; tt < 4; ++tt) {
        const int ti = t4 * 4 + tt;           // tile 0..255
        const int ty = ti >> 4, tx = ti & 15;
        const int py0 = ty * 16 - 1, px0 = tx * 16 - 1;
        __syncthreads();
        for (int i = tid; i < 18 * 324; i += 256) {
            const int ch = i / 324; const int r = i - ch * 324;
            const int ry = r / 18,  rx = r - ry * 18;
            const int py = py0 + ry, px = px0 + rx;
            const int s = ch / 6, j = ch - s * 6;
            const int cg = s * 48 + h * 6 + j;         // global qkv channel
            float v = 0.f;
            if ((unsigned)py < 256u && (unsigned)px < 256u)
                v = qkv[(((size_t)b * QKVC + cg) << 16) + py * 256 + px];
            tile[ch][r] = v;
        }
        __syncthreads();

        float q[6], k[6], vv[6];
#pragma unroll
        for (int s = 0; s < 3; ++s) {
#pragma unroll
            for (int j = 0; j < 6; ++j) {
                const int ch = s * 6 + j;
                const int cg = s * 48 + h * 6 + j;
                float acc = bdw[cg];
#pragma unroll
                for (int ky = 0; ky < 3; ++ky)
#pragma unroll
                    for (int kx = 0; kx < 3; ++kx)
                        acc += tile[ch][(iy + ky) * 18 + (ix + kx)] * wdw[cg * 9 + ky * 3 + kx];
                if (s == 0) q[j] = acc; else if (s == 1) k[j] = acc; else vv[j] = acc;
            }
        }
        const int p = (ty * 16 + iy) * 256 + (tx * 16 + ix);
#pragma unroll
        for (int j = 0; j < 6; ++j)
            vout[(((size_t)b * CH + h * 6 + j) << 16) + p] = vv[j];
#pragma unroll
        for (int c = 0; c < 6; ++c) {
            qn2[c] += q[c] * q[c];
            kn2[c] += k[c] * k[c];
#pragma unroll
            for (int d = 0; d < 6; ++d) S[c][d] += q[c] * k[d];
        }
    }

    // block reduction of 48 partials -> one atomicAdd per value per block
    const int lane = tid & 63, wv = tid >> 6;
    int idx = 0;
#define RED1(VAL) { float r_ = (VAL);                                  \
        for (int o_ = 32; o_; o_ >>= 1) r_ += __shfl_down(r_, o_);     \
        if (lane == 0) red[wv][idx] = r_;  ++idx; }
#pragma unroll
    for (int c = 0; c < 6; ++c)
#pragma unroll
        for (int d = 0; d < 6; ++d) RED1(S[c][d]);
#pragma unroll
    for (int c = 0; c < 6; ++c) RED1(qn2[c]);
#pragma unroll
    for (int c = 0; c < 6; ++c) RED1(kn2[c]);
#undef RED1
    __syncthreads();
    if (tid < 48) {
        const float s = red[0][tid] + red[1][tid] + red[2][tid] + red[3][tid];
        atomicAdd(&stats[((size_t)b * HEADS + h) * 48 + tid], s);
    }
}

// ---------------------------------------------------------------------------
// K3: per batch: cosine-sim logits -> softmax -> attn[8][6][6];
// fold with W_proj:  M[o][h*6+d] = sum_c Wproj[o][h*6+c] * attn[h][c][d]
// ---------------------------------------------------------------------------
__global__ __launch_bounds__(256) void k3_attn(
    const float* __restrict__ stats, const float* __restrict__ scale,
    const float* __restrict__ wproj, float* __restrict__ M)
{
    const int b = blockIdx.x;
    __shared__ float attn[HEADS][6][6];
    const int tid = threadIdx.x;
    if (tid < 48) {
        const int h = tid / 6, c = tid - h * 6;
        const float* st = stats + ((size_t)b * HEADS + h) * 48;
        const float qn = fmaxf(sqrtf(st[36 + c]), 1e-12f);
        const float sc = scale[h];
        float s[6]; float mx = -1e30f;
#pragma unroll
        for (int d = 0; d < 6; ++d) {
            const float kn = fmaxf(sqrtf(st[42 + d]), 1e-12f);
            s[d] = st[c * 6 + d] / (qn * kn) * sc;
            mx = fmaxf(mx, s[d]);
        }
        float sum = 0.f;
#pragma unroll
        for (int d = 0; d < 6; ++d) { s[d] = expf(s[d] - mx); sum += s[d]; }
        const float inv = 1.f / sum;
#pragma unroll
        for (int d = 0; d < 6; ++d) attn[h][c][d] = s[d] * inv;
    }
    __syncthreads();
    for (int e = tid; e < 48 * 48; e += 256) {
        const int o = e / 48; const int i = e - o * 48;
        const int h = i / 6,  d = i - h * 6;
        float acc = 0.f;
#pragma unroll
        for (int c = 0; c < 6; ++c) acc += wproj[o * 48 + h * 6 + c] * attn[h][c][d];
        M[(size_t)b * 2304 + e] = acc;
    }
}

// ---------------------------------------------------------------------------
// K4: x1 = x + M_b @ v + b_proj   (writes x1 into d_out)
// ---------------------------------------------------------------------------
__global__ __launch_bounds__(256) void k4_pvproj(
    const float* __restrict__ x, const float* __restrict__ vbuf,
    const float* __restrict__ M, const float* __restrict__ bproj,
    float* __restrict__ x1)
{
    const int tid = threadIdx.x;
    const int b = blockIdx.x >> 8;
    const int p = ((blockIdx.x & 255) << 8) | tid;
    const float* Mb = M + (size_t)b * 2304;
    float v[CH];
    const float* vb = vbuf + ((size_t)b * CH << 16) + p;
#pragma unroll
    for (int c = 0; c < CH; ++c) v[c] = vb[(size_t)c << 16];
    const float* xb = x + ((size_t)b * CH << 16) + p;
    float* ob = x1 + ((size_t)b * CH << 16) + p;
    for (int o = 0; o < CH; ++o) {
        float acc = bproj[o];
#pragma unroll
        for (int c = 0; c < CH; ++c) acc += Mb[o * CH + c] * v[c];
        ob[(size_t)o << 16] = xb[(size_t)o << 16] + acc;
    }
}

// ---------------------------------------------------------------------------
// K5: per-pixel LayerNorm + 1x1 conv to 192 hidden channels.
// ---------------------------------------------------------------------------
__global__ __launch_bounds__(256) void k5_ln_f1(
    const float* __restrict__ x1, const float* __restrict__ ln_g, const float* __restrict__ ln_b,
    const float* __restrict__ w1, const float* __restrict__ b1,
    float* __restrict__ h1)
{
    const int tid = threadIdx.x;
    const int b = blockIdx.x >> 8;
    const int p = ((blockIdx.x & 255) << 8) | tid;
    const float* xb = x1 + ((size_t)b * CH << 16) + p;
    float y[CH];
    float mu = 0.f;
#pragma unroll
    for (int c = 0; c < CH; ++c) { y[c] = xb[(size_t)c << 16]; mu += y[c]; }
    mu *= (1.0f / CH);
    float var = 0.f;
#pragma unroll
    for (int c = 0; c < CH; ++c) { float d = y[c] - mu; var += d * d; }
    const float rs = rsqrtf(var * (1.0f / CH) + 1e-5f);
#pragma unroll
    for (int c = 0; c < CH; ++c) y[c] = (y[c] - mu) * rs * ln_g[c] + ln_b[c];

    float* hb = h1 + ((size_t)b * HID << 16) + p;
    for (int o = 0; o < HID; ++o) {
        float acc = b1[o];
#pragma unroll
        for (int c = 0; c < CH; ++c) acc += w1[o * CH + c] * y[c];
        hb[(size_t)o << 16] = acc;
    }
}

// ---------------------------------------------------------------------------
// K6: dw3x3 over 192 channels (in 4 LDS-staged groups of 48) + exact GELU +
// 1x1 conv back to 48 + residual. Reads/writes d_out in place (own pixel only).
// ---------------------------------------------------------------------------
__global__ __launch_bounds__(256) void k6_ffn2(
    const float* __restrict__ h1, const float* __restrict__ wfdw, const float* __restrict__ bfdw,
    const float* __restrict__ w2, const float* __restrict__ b2,
    float* __restrict__ xio)
{
    __shared__ float tile[48][324];     // 62.2 KB
    const int tid = threadIdx.x;
    const int blk = blockIdx.x;         // B * 256 tiles
    const int b = blk >> 8; const int ti = blk & 255;
    const int ty = ti >> 4, tx = ti & 15;
    const int py0 = ty * 16 - 1, px0 = tx * 16 - 1;
    const int iy = tid >> 4, ix = tid & 15;

    float acc[CH];
#pragma unroll
    for (int o = 0; o < CH; ++o) acc[o] = b2[o];

    for (int gr = 0; gr < 4; ++gr) {
        __syncthreads();
        for (int i = tid; i < 48 * 324; i += 256) {
            const int ch = i / 324; const int r = i - ch * 324;
            const int ry = r / 18,  rx = r - ry * 18;
            const int py = py0 + ry, px = px0 + rx;
            float v = 0.f;
            if ((unsigned)py < 256u && (unsigned)px < 256u)
                v = h1[(((size_t)b * HID + gr * 48 + ch) << 16) + py * 256 + px];
            tile[ch][r] = v;
        }
        __syncthreads();

        float gl[48];
#pragma unroll
        for (int ch = 0; ch < 48; ++ch) {
            const int gc = gr * 48 + ch;
            float d = bfdw[gc];
#pragma unroll
            for (int ky = 0; ky < 3; ++ky)
#pragma unroll
                for (int kx = 0; kx < 3; ++kx)
                    d += tile[ch][(iy + ky) * 18 + (ix + kx)] * wfdw[gc * 9 + ky * 3 + kx];
            gl[ch] = 0.5f * d * (1.f + erff(d * 0.70710678118654752f));
        }
        for (int o = 0; o < CH; ++o) {
            float a = acc[o];
#pragma unroll
            for (int ch = 0; ch < 48; ++ch) a += w2[o * HID + gr * 48 + ch] * gl[ch];
            acc[o] = a;
        }
    }

    const int p = (ty * 16 + iy) * 256 + (tx * 16 + ix);
    float* ob = xio + ((size_t)b * CH << 16) + p;
#pragma unroll
    for (int o = 0; o < CH; ++o) ob[(size_t)o << 16] += acc[o];
}

// ---------------------------------------------------------------------------
extern "C" void kernel_launch(void* const* d_in, const int* in_sizes, int n_in,
                              void* d_out, int out_size, void* d_ws, size_t ws_size,
                              hipStream_t stream)
{
    const float* x      = (const float*)d_in[0];
    const float* ln1_g  = (const float*)d_in[1];
    const float* ln1_b  = (const float*)d_in[2];
    const float* w_qkv  = (const float*)d_in[3];
    const float* b_qkv  = (const float*)d_in[4];
    const float* w_dw   = (const float*)d_in[5];
    const float* b_dw   = (const float*)d_in[6];
    const float* scale  = (const float*)d_in[7];
    const float* w_proj = (const float*)d_in[8];
    const float* b_proj = (const float*)d_in[9];
    const float* ln2_g  = (const float*)d_in[10];
    const float* ln2_b  = (const float*)d_in[11];
    const float* w_f1   = (const float*)d_in[12];
    const float* b_f1   = (const float*)d_in[13];
    const float* w_fdw  = (const float*)d_in[14];
    const float* b_fdw  = (const float*)d_in[15];
    const float* w_f2   = (const float*)d_in[16];
    const float* b_f2   = (const float*)d_in[17];
    float* out = (float*)d_out;

    // Workspace layout (floats):
    //   [0)                qkv (B*144*HW), later reused as h1 (B*192*HW)
    //   [50331648)         vbuf (B*48*HW)
    //   [62914560)         stats (1536, padded 2048)
    //   [62916608)         M (B*2304)
    float* ws    = (float*)d_ws;
    float* qkv   = ws;                       // also h1
    float* vbuf  = ws + (size_t)50331648;
    float* stats = ws + (size_t)62914560;
    float* M     = ws + (size_t)62916608;

    hipMemsetAsync(stats, 0, 1536 * sizeof(float), stream);

    k1_ln_qkv <<<dim3(BATCH * 256), dim3(256), 0, stream>>>(x, ln1_g, ln1_b, w_qkv, b_qkv, qkv);
    k2_dw_gram<<<dim3(BATCH * HEADS * 64), dim3(256), 0, stream>>>(qkv, w_dw, b_dw, vbuf, stats);
    k3_attn   <<<dim3(BATCH), dim3(256), 0, stream>>>(stats, scale, w_proj, M);
    k4_pvproj <<<dim3(BATCH * 256), dim3(256), 0, stream>>>(x, vbuf, M, b_proj, out);
    k5_ln_f1  <<<dim3(BATCH * 256), dim3(256), 0, stream>>>(out, ln2_g, ln2_b, w_f1, b_f1, qkv);
    k6_ffn2   <<<dim3(BATCH * 256), dim3(256), 0, stream>>>(qkv, w_fdw, b_fdw, w_f2, b_f2, out);
}

// Round 2
// 1063.012 us; speedup vs baseline: 1.1577x; 1.1577x over previous
//
#include <hip/hip_runtime.h>
#include <math.h>

#define BATCH 4
#define CH    48
#define QKVC  144
#define HID   192
#define HEADS 8
#define IMG   256
#define HWSZ  65536

// 3x3 depthwise tap with zero 'SAME' padding. py is wave-uniform -> scalar
// branches; px checks are per-lane cndmask on the two edge lanes only.
__device__ __forceinline__ float dw9(const float* __restrict__ base, int py, int px,
                                     const float* __restrict__ w9)
{
    float a = 0.f;
    const int idx = (py << 8) + px;
#pragma unroll
    for (int dy = -1; dy <= 1; ++dy) {
        if ((unsigned)(py + dy) < 256u) {
#pragma unroll
            for (int dx = -1; dx <= 1; ++dx) {
                float v = 0.f;
                if ((unsigned)(px + dx) < 256u) v = base[idx + (dy << 8) + dx];
                a += v * w9[(dy + 1) * 3 + (dx + 1)];
            }
        }
    }
    return a;
}

// ---------------------------------------------------------------------------
// K0: transpose w_f2 (48x192) -> w2t (192x48) so K6 reads contiguous rows.
// ---------------------------------------------------------------------------
__global__ __launch_bounds__(256) void k0_w2t(const float* __restrict__ w2, float* __restrict__ w2t)
{
    const int e = blockIdx.x * 256 + threadIdx.x;
    if (e < CH * HID) {
        const int o = e / HID, gc = e - o * HID;
        w2t[gc * CH + o] = w2[e];
    }
}

// ---------------------------------------------------------------------------
// K1: per-pixel LayerNorm over C=48 + 1x1 conv to 144 qkv channels.
// ---------------------------------------------------------------------------
__global__ __launch_bounds__(256) void k1_ln_qkv(
    const float* __restrict__ x, const float* __restrict__ ln_g, const float* __restrict__ ln_b,
    const float* __restrict__ wq, const float* __restrict__ bq,
    float* __restrict__ qkv)
{
    const int tid = threadIdx.x;
    const int b = blockIdx.x >> 8;
    const int p = ((blockIdx.x & 255) << 8) | tid;
    const float* xb = x + ((size_t)b * CH << 16) + p;
    float y[CH];
    float mu = 0.f;
#pragma unroll
    for (int c = 0; c < CH; ++c) { y[c] = xb[(size_t)c << 16]; mu += y[c]; }
    mu *= (1.0f / CH);
    float var = 0.f;
#pragma unroll
    for (int c = 0; c < CH; ++c) { float d = y[c] - mu; var += d * d; }
    const float rs = rsqrtf(var * (1.0f / CH) + 1e-5f);
#pragma unroll
    for (int c = 0; c < CH; ++c) y[c] = (y[c] - mu) * rs * ln_g[c] + ln_b[c];

    float* qb = qkv + ((size_t)b * QKVC << 16) + p;
    for (int o = 0; o < QKVC; ++o) {
        float acc = bq[o];
#pragma unroll
        for (int c = 0; c < CH; ++c) acc += wq[o * CH + c] * y[c];
        qb[(size_t)o << 16] = acc;
    }
}

// ---------------------------------------------------------------------------
// K2: global-direct depthwise 3x3 for one head's 18 channels (6q,6k,6v).
// Block = 512 threads covering a 64x8 pixel tile. Writes dw'd v; block-reduces
// Gram S[6][6] + q/k squared norms -> atomicAdd into stats[b][h][48].
// ---------------------------------------------------------------------------
__global__ __launch_bounds__(512) void k2_dw_gram(
    const float* __restrict__ qkv, const float* __restrict__ wdw, const float* __restrict__ bdw,
    float* __restrict__ vout, float* __restrict__ stats)
{
    __shared__ float red[8][48];
    const int tid = threadIdx.x;
    int blk = blockIdx.x;
    const int tx = blk & 3;        blk >>= 2;
    const int ty = blk & 31;       blk >>= 5;
    const int h  = blk & 7;        blk >>= 3;
    const int b  = blk;
    const int px = (tx << 6) | (tid & 63);
    const int py = (ty << 3) | (tid >> 6);     // wave-uniform
    const int idx = (py << 8) + px;

    float q[6], k[6];
#pragma unroll
    for (int s = 0; s < 3; ++s) {
#pragma unroll
        for (int j = 0; j < 6; ++j) {
            const int cg = s * 48 + h * 6 + j;
            const float* base = qkv + ((size_t)(b * QKVC + cg) << 16);
            float a = bdw[cg] + dw9(base, py, px, wdw + cg * 9);
            if (s == 0) q[j] = a;
            else if (s == 1) k[j] = a;
            else vout[((size_t)(b * CH + h * 6 + j) << 16) + idx] = a;
        }
    }

    float S[48];
#pragma unroll
    for (int c = 0; c < 6; ++c)
#pragma unroll
        for (int d = 0; d < 6; ++d) S[c * 6 + d] = q[c] * k[d];
#pragma unroll
    for (int c = 0; c < 6; ++c) { S[36 + c] = q[c] * q[c]; S[42 + c] = k[c] * k[c]; }

    const int lane = tid & 63, wv = tid >> 6;
#pragma unroll
    for (int i = 0; i < 48; ++i) {
        float r = S[i];
        for (int o = 32; o; o >>= 1) r += __shfl_down(r, o);
        if (lane == 0) red[wv][i] = r;
    }
    __syncthreads();
    if (tid < 48) {
        float s = 0.f;
#pragma unroll
        for (int w = 0; w < 8; ++w) s += red[w][tid];
        atomicAdd(&stats[((size_t)b * HEADS + h) * 48 + tid], s);
    }
}

// ---------------------------------------------------------------------------
// K3: cosine-sim logits -> softmax -> attn; fold with W_proj into M (48x48/batch)
// ---------------------------------------------------------------------------
__global__ __launch_bounds__(256) void k3_attn(
    const float* __restrict__ stats, const float* __restrict__ scale,
    const float* __restrict__ wproj, float* __restrict__ M)
{
    const int b = blockIdx.x;
    __shared__ float attn[HEADS][6][6];
    const int tid = threadIdx.x;
    if (tid < 48) {
        const int h = tid / 6, c = tid - h * 6;
        const float* st = stats + ((size_t)b * HEADS + h) * 48;
        const float qn = fmaxf(sqrtf(st[36 + c]), 1e-12f);
        const float sc = scale[h];
        float s[6]; float mx = -1e30f;
#pragma unroll
        for (int d = 0; d < 6; ++d) {
            const float kn = fmaxf(sqrtf(st[42 + d]), 1e-12f);
            s[d] = st[c * 6 + d] / (qn * kn) * sc;
            mx = fmaxf(mx, s[d]);
        }
        float sum = 0.f;
#pragma unroll
        for (int d = 0; d < 6; ++d) { s[d] = expf(s[d] - mx); sum += s[d]; }
        const float inv = 1.f / sum;
#pragma unroll
        for (int d = 0; d < 6; ++d) attn[h][c][d] = s[d] * inv;
    }
    __syncthreads();
    for (int e = tid; e < 48 * 48; e += 256) {
        const int o = e / 48; const int i = e - o * 48;
        const int h = i / 6,  d = i - h * 6;
        float acc = 0.f;
#pragma unroll
        for (int c = 0; c < 6; ++c) acc += wproj[o * 48 + h * 6 + c] * attn[h][c][d];
        M[(size_t)b * 2304 + e] = acc;
    }
}

// ---------------------------------------------------------------------------
// K45: fused  x1 = x + M_b@v + b_proj  (store to d_out)  then per-pixel LN +
// 1x1 conv to 192 hidden channels (store h1).
// ---------------------------------------------------------------------------
__global__ __launch_bounds__(256) void k45_pvproj_ln_f1(
    const float* __restrict__ x, const float* __restrict__ vbuf,
    const float* __restrict__ M, const float* __restrict__ bproj,
    const float* __restrict__ ln_g, const float* __restrict__ ln_b,
    const float* __restrict__ w1, const float* __restrict__ b1,
    float* __restrict__ x1, float* __restrict__ h1)
{
    const int tid = threadIdx.x;
    const int b = blockIdx.x >> 8;
    const int p = ((blockIdx.x & 255) << 8) | tid;
    const float* Mb = M + (size_t)b * 2304;
    float v[CH];
    const float* vb = vbuf + ((size_t)b * CH << 16) + p;
#pragma unroll
    for (int c = 0; c < CH; ++c) v[c] = vb[(size_t)c << 16];
    const float* xb = x + ((size_t)b * CH << 16) + p;
    float* ob = x1 + ((size_t)b * CH << 16) + p;

    float y[CH];
    float mu = 0.f;
    for (int o = 0; o < CH; ++o) {
        float acc = bproj[o];
#pragma unroll
        for (int c = 0; c < CH; ++c) acc += Mb[o * CH + c] * v[c];
        acc += xb[(size_t)o << 16];
        ob[(size_t)o << 16] = acc;
        y[o] = acc; mu += acc;
    }
    mu *= (1.0f / CH);
    float var = 0.f;
#pragma unroll
    for (int c = 0; c < CH; ++c) { float d = y[c] - mu; var += d * d; }
    const float rs = rsqrtf(var * (1.0f / CH) + 1e-5f);
#pragma unroll
    for (int c = 0; c < CH; ++c) y[c] = (y[c] - mu) * rs * ln_g[c] + ln_b[c];

    float* hb = h1 + ((size_t)b * HID << 16) + p;
    for (int o = 0; o < HID; ++o) {
        float acc = b1[o];
#pragma unroll
        for (int c = 0; c < CH; ++c) acc += w1[o * CH + c] * y[c];
        hb[(size_t)o << 16] = acc;
    }
}

// ---------------------------------------------------------------------------
// K6: global-direct dw3x3 over 192 channels + exact GELU + 1x1 conv to 48 +
// residual. Block = 512 threads covering 64x8 tile; no LDS.
// ---------------------------------------------------------------------------
__global__ __launch_bounds__(512) void k6_ffn2(
    const float* __restrict__ h1, const float* __restrict__ wfdw, const float* __restrict__ bfdw,
    const float* __restrict__ w2t, const float* __restrict__ b2,
    float* __restrict__ xio)
{
    const int tid = threadIdx.x;
    int blk = blockIdx.x;
    const int tx = blk & 3;        blk >>= 2;
    const int ty = blk & 31;       blk >>= 5;
    const int b  = blk;
    const int px = (tx << 6) | (tid & 63);
    const int py = (ty << 3) | (tid >> 6);     // wave-uniform
    const int idx = (py << 8) + px;

    float acc[CH];
#pragma unroll
    for (int o = 0; o < CH; ++o) acc[o] = b2[o];

    for (int gc = 0; gc < HID; ++gc) {
        const float* base = h1 + ((size_t)(b * HID + gc) << 16);
        const float d = bfdw[gc] + dw9(base, py, px, wfdw + gc * 9);
        const float g = 0.5f * d * (1.f + erff(d * 0.70710678118654752f));
        const float* wrow = w2t + gc * CH;
#pragma unroll
        for (int o = 0; o < CH; ++o) acc[o] += wrow[o] * g;
    }

    float* ob = xio + ((size_t)b * CH << 16) + idx;
#pragma unroll
    for (int o = 0; o < CH; ++o) ob[(size_t)o << 16] += acc[o];
}

// ---------------------------------------------------------------------------
extern "C" void kernel_launch(void* const* d_in, const int* in_sizes, int n_in,
                              void* d_out, int out_size, void* d_ws, size_t ws_size,
                              hipStream_t stream)
{
    const float* x      = (const float*)d_in[0];
    const float* ln1_g  = (const float*)d_in[1];
    const float* ln1_b  = (const float*)d_in[2];
    const float* w_qkv  = (const float*)d_in[3];
    const float* b_qkv  = (const float*)d_in[4];
    const float* w_dw   = (const float*)d_in[5];
    const float* b_dw   = (const float*)d_in[6];
    const float* scale  = (const float*)d_in[7];
    const float* w_proj = (const float*)d_in[8];
    const float* b_proj = (const float*)d_in[9];
    const float* ln2_g  = (const float*)d_in[10];
    const float* ln2_b  = (const float*)d_in[11];
    const float* w_f1   = (const float*)d_in[12];
    const float* b_f1   = (const float*)d_in[13];
    const float* w_fdw  = (const float*)d_in[14];
    const float* b_fdw  = (const float*)d_in[15];
    const float* w_f2   = (const float*)d_in[16];
    const float* b_f2   = (const float*)d_in[17];
    float* out = (float*)d_out;

    // Workspace (floats):
    //   [0)          qkv (B*144*HW), reused as h1 (B*192*HW)
    //   [50331648)   vbuf (B*48*HW)
    //   [62914560)   stats (1536, padded to 2048)
    //   [62916608)   M (B*2304 = 9216)
    //   [62925824)   w2t (192*48 = 9216)
    float* ws    = (float*)d_ws;
    float* qkv   = ws;
    float* vbuf  = ws + (size_t)50331648;
    float* stats = ws + (size_t)62914560;
    float* M     = ws + (size_t)62916608;
    float* w2t   = ws + (size_t)62925824;

    hipMemsetAsync(stats, 0, 1536 * sizeof(float), stream);

    k0_w2t          <<<dim3(36),               dim3(256), 0, stream>>>(w_f2, w2t);
    k1_ln_qkv       <<<dim3(BATCH * 256),      dim3(256), 0, stream>>>(x, ln1_g, ln1_b, w_qkv, b_qkv, qkv);
    k2_dw_gram      <<<dim3(BATCH * HEADS * 128), dim3(512), 0, stream>>>(qkv, w_dw, b_dw, vbuf, stats);
    k3_attn         <<<dim3(BATCH),            dim3(256), 0, stream>>>(stats, scale, w_proj, M);
    k45_pvproj_ln_f1<<<dim3(BATCH * 256),      dim3(256), 0, stream>>>(x, vbuf, M, b_proj,
                                                                       ln2_g, ln2_b, w_f1, b_f1, out, qkv);
    k6_ffn2         <<<dim3(BATCH * 128),      dim3(512), 0, stream>>>(qkv, w_fdw, b_fdw, w2t, b_f2, out);
}